// Round 2
// baseline (127.421 us; speedup 1.0000x reference)
//
#include <hip/hip_runtime.h>
#include <math.h>

constexpr int B_ = 4, C_ = 32, L_ = 256, M_ = 256, F_ = 8, N_ = 64;

// One wave (64 threads) per (b, l). Lane i covers m = 4i..4i+3 via float4.
// Weights for this l are interpolated once into LDS (512 floats) and read
// back as wave-uniform b128 broadcasts (conflict-free).
__global__ __launch_bounds__(64) void sphereconv_kernel(
    const float* __restrict__ xr, const float* __restrict__ xi,
    const float* __restrict__ wr, const float* __restrict__ wi,
    float* __restrict__ out)
{
    __shared__ float ws[C_ * 16];   // [c][ wr f0..7 | wi f0..7 ]

    const int b    = blockIdx.x >> 8;        // / L_
    const int l    = blockIdx.x & (L_ - 1);
    const int lane = threadIdx.x;            // 0..63

    // interp coords (uniform): t = l/(L-1)*(N-1)
    const float t = ((float)l / (float)(L_ - 1)) * (float)(N_ - 1);
    int lo = (int)floorf(t);
    if (lo > N_ - 2) lo = N_ - 2;
    const float frac = t - (float)lo;

    // stage 512 interpolated weight floats: 8 per thread
#pragma unroll
    for (int i = 0; i < 8; ++i) {
        const int idx = lane * 8 + i;        // 0..511
        const int c   = idx >> 4;
        const int j   = idx & 15;
        const int f   = j & 7;
        const float* w = (j & 8) ? wi : wr;
        const int base = (f * C_ + c) * N_ + lo;   // w layout (F,C,N,1)
        ws[c * 16 + j] = w[base] * (1.0f - frac) + w[base + 1] * frac;
    }
    __syncthreads();

    float4 accr[F_], acci[F_];
#pragma unroll
    for (int f = 0; f < F_; ++f) {
        accr[f] = make_float4(0.f, 0.f, 0.f, 0.f);
        acci[f] = make_float4(0.f, 0.f, 0.f, 0.f);
    }

    const size_t strideC4 = (size_t)L_ * M_ / 4;   // c-stride in float4 units
    const size_t xoff = ((size_t)b * C_) * L_ * M_ + (size_t)l * M_ + lane * 4;
    const float4* xr4 = (const float4*)(xr + xoff);
    const float4* xi4 = (const float4*)(xi + xoff);

#pragma unroll 4
    for (int c = 0; c < C_; ++c) {
        const float4 vr = xr4[c * strideC4];
        const float4 vi = xi4[c * strideC4];
        const float4 w0 = *(const float4*)&ws[c * 16 + 0];
        const float4 w1 = *(const float4*)&ws[c * 16 + 4];
        const float4 u0 = *(const float4*)&ws[c * 16 + 8];
        const float4 u1 = *(const float4*)&ws[c * 16 + 12];
        const float wrf[8] = {w0.x, w0.y, w0.z, w0.w, w1.x, w1.y, w1.z, w1.w};
        const float wif[8] = {u0.x, u0.y, u0.z, u0.w, u1.x, u1.y, u1.z, u1.w};
#pragma unroll
        for (int f = 0; f < F_; ++f) {
            const float a = wrf[f], bb = wif[f];
            accr[f].x += a * vr.x - bb * vi.x;  acci[f].x += a * vi.x + bb * vr.x;
            accr[f].y += a * vr.y - bb * vi.y;  acci[f].y += a * vi.y + bb * vr.y;
            accr[f].z += a * vr.z - bb * vi.z;  acci[f].z += a * vi.z + bb * vr.z;
            accr[f].w += a * vr.w - bb * vi.w;  acci[f].w += a * vi.w + bb * vr.w;
        }
    }

    const float scale = sqrtf(1.0f + (float)l) * (1.0f / (float)C_);
    // out layout: (((s*B + b)*F + f)*L + l)*M + m ; s=0 real(relu), s=1 imag
    const size_t o0      = (((size_t)b * F_) * L_ + l) * M_ + lane * 4;
    const size_t imagOff = (size_t)B_ * F_ * L_ * M_;
    const size_t fStride = (size_t)L_ * M_;
#pragma unroll
    for (int f = 0; f < F_; ++f) {
        float4 yr, yi;
        yr.x = fmaxf(accr[f].x * scale, 0.f);
        yr.y = fmaxf(accr[f].y * scale, 0.f);
        yr.z = fmaxf(accr[f].z * scale, 0.f);
        yr.w = fmaxf(accr[f].w * scale, 0.f);
        yi.x = acci[f].x * scale;
        yi.y = acci[f].y * scale;
        yi.z = acci[f].z * scale;
        yi.w = acci[f].w * scale;
        *(float4*)(out + o0 + (size_t)f * fStride)           = yr;
        *(float4*)(out + o0 + (size_t)f * fStride + imagOff) = yi;
    }
}

extern "C" void kernel_launch(void* const* d_in, const int* in_sizes, int n_in,
                              void* d_out, int out_size, void* d_ws, size_t ws_size,
                              hipStream_t stream) {
    const float* xr = (const float*)d_in[0];
    const float* xi = (const float*)d_in[1];
    const float* wr = (const float*)d_in[2];
    const float* wi = (const float*)d_in[3];
    float* out = (float*)d_out;
    sphereconv_kernel<<<dim3(B_ * L_), dim3(64), 0, stream>>>(xr, xi, wr, wi, out);
}

// Round 3
// 114.863 us; speedup vs baseline: 1.1093x; 1.1093x over previous
//
#include <hip/hip_runtime.h>
#include <math.h>

constexpr int B_ = 4, C_ = 32, L_ = 256, M_ = 256, F_ = 8, N_ = 64;

// One (b,l) per 128-thread block (2 waves). Lane tid covers m = 2*tid, 2*tid+1
// via float2 loads. Accumulator footprint = 8f * 2(r/i) * float2 = 32 floats
// (fits registers; R2's 64-float acc spilled at the compiler's 60-VGPR default).
// __launch_bounds__(128,4): cap 128 VGPRs, 16 waves/CU allowed.
__global__ __launch_bounds__(128, 4) void sphereconv_kernel(
    const float* __restrict__ xr, const float* __restrict__ xi,
    const float* __restrict__ wr, const float* __restrict__ wi,
    float* __restrict__ out)
{
    __shared__ float ws[C_ * 16];   // [c][ wr f0..7 | wi f0..7 ]

    const int b   = blockIdx.x >> 8;        // / L_
    const int l   = blockIdx.x & (L_ - 1);
    const int tid = threadIdx.x;            // 0..127

    // interp coords (uniform): t = l/(L-1)*(N-1)
    const float t = ((float)l / (float)(L_ - 1)) * (float)(N_ - 1);
    int lo = (int)floorf(t);
    if (lo > N_ - 2) lo = N_ - 2;
    const float frac = t - (float)lo;

    // stage 512 interpolated weight floats: 4 per thread
#pragma unroll
    for (int i = tid; i < C_ * 16; i += 128) {
        const int c = i >> 4;
        const int j = i & 15;
        const int f = j & 7;
        const float* w = (j & 8) ? wi : wr;
        const int base = (f * C_ + c) * N_ + lo;   // w layout (F,C,N,1)
        ws[c * 16 + j] = w[base] * (1.0f - frac) + w[base + 1] * frac;
    }
    __syncthreads();

    float2 accr[F_], acci[F_];
#pragma unroll
    for (int f = 0; f < F_; ++f) {
        accr[f] = make_float2(0.f, 0.f);
        acci[f] = make_float2(0.f, 0.f);
    }

    const size_t strideC2 = (size_t)L_ * M_ / 2;   // c-stride in float2 units
    const size_t xoff = ((size_t)b * C_) * L_ * M_ + (size_t)l * M_ + tid * 2;
    const float2* xr2 = (const float2*)(xr + xoff);
    const float2* xi2 = (const float2*)(xi + xoff);

#define CX(f, A, Bv)                                          \
    accr[f].x = fmaf(A, vr.x, fmaf(-(Bv), vi.x, accr[f].x));  \
    accr[f].y = fmaf(A, vr.y, fmaf(-(Bv), vi.y, accr[f].y));  \
    acci[f].x = fmaf(A, vi.x, fmaf((Bv), vr.x, acci[f].x));   \
    acci[f].y = fmaf(A, vi.y, fmaf((Bv), vr.y, acci[f].y));

#pragma unroll 4
    for (int c = 0; c < C_; ++c) {
        const float2 vr = xr2[c * strideC2];
        const float2 vi = xi2[c * strideC2];
        const float4 a0 = *(const float4*)&ws[c * 16 + 0];   // wr f0..3
        const float4 a1 = *(const float4*)&ws[c * 16 + 4];   // wr f4..7
        const float4 b0 = *(const float4*)&ws[c * 16 + 8];   // wi f0..3
        const float4 b1 = *(const float4*)&ws[c * 16 + 12];  // wi f4..7
        CX(0, a0.x, b0.x)
        CX(1, a0.y, b0.y)
        CX(2, a0.z, b0.z)
        CX(3, a0.w, b0.w)
        CX(4, a1.x, b1.x)
        CX(5, a1.y, b1.y)
        CX(6, a1.z, b1.z)
        CX(7, a1.w, b1.w)
    }
#undef CX

    const float scale = sqrtf(1.0f + (float)l) * (1.0f / (float)C_);
    // out layout: (((s*B + b)*F + f)*L + l)*M + m ; s=0 real(relu), s=1 imag
    const size_t o0      = (((size_t)b * F_) * L_ + l) * M_ + tid * 2;
    const size_t imagOff = (size_t)B_ * F_ * L_ * M_;
    const size_t fStride = (size_t)L_ * M_;
#pragma unroll
    for (int f = 0; f < F_; ++f) {
        float2 yr, yi;
        yr.x = fmaxf(accr[f].x * scale, 0.f);
        yr.y = fmaxf(accr[f].y * scale, 0.f);
        yi.x = acci[f].x * scale;
        yi.y = acci[f].y * scale;
        *(float2*)(out + o0 + (size_t)f * fStride)           = yr;
        *(float2*)(out + o0 + (size_t)f * fStride + imagOff) = yi;
    }
}

extern "C" void kernel_launch(void* const* d_in, const int* in_sizes, int n_in,
                              void* d_out, int out_size, void* d_ws, size_t ws_size,
                              hipStream_t stream) {
    const float* xr = (const float*)d_in[0];
    const float* xi = (const float*)d_in[1];
    const float* wr = (const float*)d_in[2];
    const float* wi = (const float*)d_in[3];
    float* out = (float*)d_out;
    sphereconv_kernel<<<dim3(B_ * L_), dim3(128), 0, stream>>>(xr, xi, wr, wi, out);
}

// Round 4
// 107.922 us; speedup vs baseline: 1.1807x; 1.0643x over previous
//
#include <hip/hip_runtime.h>
#include <math.h>

constexpr int B_ = 4, C_ = 32, L_ = 256, M_ = 256, F_ = 8, N_ = 64;

// One (b,l) per 256-thread block (4 waves). Waves split the C-reduction:
// group 0 (tid 0..127) does c=0..15, group 1 does c=16..31; within a group,
// thread t covers m = 2t, 2t+1 (float2). Partials combined through LDS.
// 16 waves/CU (4/SIMD) + unroll-8 (16 loads in flight/wave) for latency hiding.
__global__ __launch_bounds__(256, 4) void sphereconv_kernel(
    const float* __restrict__ xr, const float* __restrict__ xi,
    const float* __restrict__ wr, const float* __restrict__ wi,
    float* __restrict__ out)
{
    __shared__ float ws[C_ * 16];        // interpolated weights [c][wr f0..7 | wi f0..7]
    __shared__ float red[32 * 128];      // partial sums, [j][t] (lane-consecutive)

    const int b   = blockIdx.x >> 8;         // / L_
    const int l   = blockIdx.x & (L_ - 1);
    const int tid = threadIdx.x;             // 0..255
    const int grp = tid >> 7;                // c-half
    const int t   = tid & 127;               // m-pair index

    // interp coords (uniform): t_coord = l/(L-1)*(N-1)
    const float tc = ((float)l / (float)(L_ - 1)) * (float)(N_ - 1);
    int lo = (int)floorf(tc);
    if (lo > N_ - 2) lo = N_ - 2;
    const float frac = tc - (float)lo;

    // stage 512 interpolated weight floats: 2 per thread
#pragma unroll
    for (int i = tid; i < C_ * 16; i += 256) {
        const int c = i >> 4;
        const int j = i & 15;
        const int f = j & 7;
        const float* w = (j & 8) ? wi : wr;
        const int base = (f * C_ + c) * N_ + lo;   // w layout (F,C,N,1)
        ws[c * 16 + j] = w[base] * (1.0f - frac) + w[base + 1] * frac;
    }
    __syncthreads();

    float2 accr[F_], acci[F_];
#pragma unroll
    for (int f = 0; f < F_; ++f) {
        accr[f] = make_float2(0.f, 0.f);
        acci[f] = make_float2(0.f, 0.f);
    }

    const int c0 = grp * 16;
    const size_t strideC2 = (size_t)L_ * M_ / 2;   // c-stride in float2 units
    const size_t xoff = ((size_t)b * C_ + c0) * L_ * M_ + (size_t)l * M_ + t * 2;
    const float2* xr2 = (const float2*)(xr + xoff);
    const float2* xi2 = (const float2*)(xi + xoff);

#define CX(f, A, Bv)                                          \
    accr[f].x = fmaf(A, vr.x, fmaf(-(Bv), vi.x, accr[f].x));  \
    accr[f].y = fmaf(A, vr.y, fmaf(-(Bv), vi.y, accr[f].y));  \
    acci[f].x = fmaf(A, vi.x, fmaf((Bv), vr.x, acci[f].x));   \
    acci[f].y = fmaf(A, vi.y, fmaf((Bv), vr.y, acci[f].y));

#pragma unroll 8
    for (int c = 0; c < 16; ++c) {
        const float2 vr = xr2[c * strideC2];
        const float2 vi = xi2[c * strideC2];
        const float* wp = &ws[(c0 + c) * 16];
        const float4 a0 = *(const float4*)(wp + 0);   // wr f0..3
        const float4 a1 = *(const float4*)(wp + 4);   // wr f4..7
        const float4 b0 = *(const float4*)(wp + 8);   // wi f0..3
        const float4 b1 = *(const float4*)(wp + 12);  // wi f4..7
        CX(0, a0.x, b0.x)
        CX(1, a0.y, b0.y)
        CX(2, a0.z, b0.z)
        CX(3, a0.w, b0.w)
        CX(4, a1.x, b1.x)
        CX(5, a1.y, b1.y)
        CX(6, a1.z, b1.z)
        CX(7, a1.w, b1.w)
    }
#undef CX

    // cross-group combine: group 1 stores partials, group 0 adds + epilogue
    if (grp == 1) {
#pragma unroll
        for (int f = 0; f < F_; ++f) {
            red[(f * 4 + 0) * 128 + t] = accr[f].x;
            red[(f * 4 + 1) * 128 + t] = accr[f].y;
            red[(f * 4 + 2) * 128 + t] = acci[f].x;
            red[(f * 4 + 3) * 128 + t] = acci[f].y;
        }
    }
    __syncthreads();
    if (grp == 0) {
        const float scale = sqrtf(1.0f + (float)l) * (1.0f / (float)C_);
        // out layout: (((s*B + b)*F + f)*L + l)*M + m ; s=0 real(relu), s=1 imag
        const size_t o0      = (((size_t)b * F_) * L_ + l) * M_ + t * 2;
        const size_t imagOff = (size_t)B_ * F_ * L_ * M_;
        const size_t fStride = (size_t)L_ * M_;
#pragma unroll
        for (int f = 0; f < F_; ++f) {
            float2 yr, yi;
            yr.x = fmaxf((accr[f].x + red[(f * 4 + 0) * 128 + t]) * scale, 0.f);
            yr.y = fmaxf((accr[f].y + red[(f * 4 + 1) * 128 + t]) * scale, 0.f);
            yi.x = (acci[f].x + red[(f * 4 + 2) * 128 + t]) * scale;
            yi.y = (acci[f].y + red[(f * 4 + 3) * 128 + t]) * scale;
            *(float2*)(out + o0 + (size_t)f * fStride)           = yr;
            *(float2*)(out + o0 + (size_t)f * fStride + imagOff) = yi;
        }
    }
}

extern "C" void kernel_launch(void* const* d_in, const int* in_sizes, int n_in,
                              void* d_out, int out_size, void* d_ws, size_t ws_size,
                              hipStream_t stream) {
    const float* xr = (const float*)d_in[0];
    const float* xi = (const float*)d_in[1];
    const float* wr = (const float*)d_in[2];
    const float* wi = (const float*)d_in[3];
    float* out = (float*)d_out;
    sphereconv_kernel<<<dim3(B_ * L_), dim3(256), 0, stream>>>(xr, xi, wr, wi, out);
}

// Round 5
// 107.840 us; speedup vs baseline: 1.1816x; 1.0008x over previous
//
#include <hip/hip_runtime.h>
#include <math.h>

constexpr int B_ = 4, C_ = 32, L_ = 256, M_ = 256, F_ = 8, N_ = 64;

// One (b,l) per 128-thread block (2 waves). Wave w reduces c-half w;
// lane covers m = 4*lane .. 4*lane+3 (float4 => 1 KB per vmem instruction).
// All 32 x-rows for the wave's c-half are preloaded into registers before
// the FMA phase: 32 KB in flight per wave (max MLP). Acc = 8f*2*float4 =
// 64 floats; data 128 regs -> needs the 256-VGPR budget of
// __launch_bounds__(128,2) (2 waves/SIMD * 4 blocks/CU = 8 waves/CU).
__global__ __launch_bounds__(128, 2) void sphereconv_kernel(
    const float* __restrict__ xr, const float* __restrict__ xi,
    const float* __restrict__ wr, const float* __restrict__ wi,
    float* __restrict__ out)
{
    __shared__ float  ws[C_ * 16];     // interpolated weights [c][wr f0..7 | wi f0..7]
    __shared__ float4 red[16 * 64];    // cross-wave partials: [f*2+s][lane]

    const int b    = blockIdx.x >> 8;        // / L_
    const int l    = blockIdx.x & (L_ - 1);
    const int tid  = threadIdx.x;            // 0..127
    const int wave = tid >> 6;               // c-half
    const int lane = tid & 63;

    // interp coords (uniform): t = l/(L-1)*(N-1)
    const float tc = ((float)l / (float)(L_ - 1)) * (float)(N_ - 1);
    int lo = (int)floorf(tc);
    if (lo > N_ - 2) lo = N_ - 2;
    const float frac = tc - (float)lo;

    // stage 512 interpolated weight floats: 4 per thread
#pragma unroll
    for (int i = tid; i < C_ * 16; i += 128) {
        const int c = i >> 4;
        const int j = i & 15;
        const int f = j & 7;
        const float* w = (j & 8) ? wi : wr;
        const int base = (f * C_ + c) * N_ + lo;   // w layout (F,C,N,1)
        ws[c * 16 + j] = w[base] * (1.0f - frac) + w[base + 1] * frac;
    }
    __syncthreads();

    const int c0 = wave * 16;
    const size_t strideC4 = (size_t)L_ * M_ / 4;   // c-stride in float4 units
    const size_t xoff = ((size_t)b * C_ + c0) * L_ * M_ + (size_t)l * M_ + lane * 4;
    const float4* xr4 = (const float4*)(xr + xoff);
    const float4* xi4 = (const float4*)(xi + xoff);

    // ---- preload phase: issue all 32 row loads before any consumption ----
    float4 xv_r[16], xv_i[16];
#pragma unroll
    for (int c = 0; c < 16; ++c) {
        xv_r[c] = xr4[c * strideC4];
        xv_i[c] = xi4[c * strideC4];
    }

    float4 accr[F_], acci[F_];
#pragma unroll
    for (int f = 0; f < F_; ++f) {
        accr[f] = make_float4(0.f, 0.f, 0.f, 0.f);
        acci[f] = make_float4(0.f, 0.f, 0.f, 0.f);
    }

#define CX(f, A, Bv)                                          \
    accr[f].x = fmaf(A, vr.x, fmaf(-(Bv), vi.x, accr[f].x));  \
    accr[f].y = fmaf(A, vr.y, fmaf(-(Bv), vi.y, accr[f].y));  \
    accr[f].z = fmaf(A, vr.z, fmaf(-(Bv), vi.z, accr[f].z));  \
    accr[f].w = fmaf(A, vr.w, fmaf(-(Bv), vi.w, accr[f].w));  \
    acci[f].x = fmaf(A, vi.x, fmaf((Bv), vr.x, acci[f].x));   \
    acci[f].y = fmaf(A, vi.y, fmaf((Bv), vr.y, acci[f].y));   \
    acci[f].z = fmaf(A, vi.z, fmaf((Bv), vr.z, acci[f].z));   \
    acci[f].w = fmaf(A, vi.w, fmaf((Bv), vr.w, acci[f].w));

    // ---- compute phase ----
#pragma unroll
    for (int c = 0; c < 16; ++c) {
        const float4 vr = xv_r[c];
        const float4 vi = xv_i[c];
        const float* wp = &ws[(c0 + c) * 16];
        const float4 a0 = *(const float4*)(wp + 0);   // wr f0..3
        const float4 a1 = *(const float4*)(wp + 4);   // wr f4..7
        const float4 b0 = *(const float4*)(wp + 8);   // wi f0..3
        const float4 b1 = *(const float4*)(wp + 12);  // wi f4..7
        CX(0, a0.x, b0.x)
        CX(1, a0.y, b0.y)
        CX(2, a0.z, b0.z)
        CX(3, a0.w, b0.w)
        CX(4, a1.x, b1.x)
        CX(5, a1.y, b1.y)
        CX(6, a1.z, b1.z)
        CX(7, a1.w, b1.w)
    }
#undef CX

    // ---- cross-wave combine: wave 1 stores, wave 0 adds + epilogue ----
    if (wave == 1) {
#pragma unroll
        for (int f = 0; f < F_; ++f) {
            red[(f * 2 + 0) * 64 + lane] = accr[f];
            red[(f * 2 + 1) * 64 + lane] = acci[f];
        }
    }
    __syncthreads();
    if (wave == 0) {
        const float scale = sqrtf(1.0f + (float)l) * (1.0f / (float)C_);
        // out layout: (((s*B + b)*F + f)*L + l)*M + m ; s=0 real(relu), s=1 imag
        const size_t o0      = (((size_t)b * F_) * L_ + l) * M_ + lane * 4;
        const size_t imagOff = (size_t)B_ * F_ * L_ * M_;
        const size_t fStride = (size_t)L_ * M_;
#pragma unroll
        for (int f = 0; f < F_; ++f) {
            const float4 pr = red[(f * 2 + 0) * 64 + lane];
            const float4 pi = red[(f * 2 + 1) * 64 + lane];
            float4 yr, yi;
            yr.x = fmaxf((accr[f].x + pr.x) * scale, 0.f);
            yr.y = fmaxf((accr[f].y + pr.y) * scale, 0.f);
            yr.z = fmaxf((accr[f].z + pr.z) * scale, 0.f);
            yr.w = fmaxf((accr[f].w + pr.w) * scale, 0.f);
            yi.x = (acci[f].x + pi.x) * scale;
            yi.y = (acci[f].y + pi.y) * scale;
            yi.z = (acci[f].z + pi.z) * scale;
            yi.w = (acci[f].w + pi.w) * scale;
            *(float4*)(out + o0 + (size_t)f * fStride)           = yr;
            *(float4*)(out + o0 + (size_t)f * fStride + imagOff) = yi;
        }
    }
}

extern "C" void kernel_launch(void* const* d_in, const int* in_sizes, int n_in,
                              void* d_out, int out_size, void* d_ws, size_t ws_size,
                              hipStream_t stream) {
    const float* xr = (const float*)d_in[0];
    const float* xi = (const float*)d_in[1];
    const float* wr = (const float*)d_in[2];
    const float* wi = (const float*)d_in[3];
    float* out = (float*)d_out;
    sphereconv_kernel<<<dim3(B_ * L_), dim3(128), 0, stream>>>(xr, xi, wr, wi, out);
}